// Round 3
// baseline (543.411 us; speedup 1.0000x reference)
//
#include <hip/hip_runtime.h>

#define DIM 64
#define KC 512
#define BLK 256

// One thread per point; x row pinned in 64 VGPRs; centroid rows read via
// wave-uniform addresses -> s_load scalar broadcasts (confirmed: SGPR=96).
//
// amdgpu_waves_per_eu(4,4): the MAX of 4 waves/EU is the critical part —
// launch_bounds' 2nd arg only sets a MIN (occupancy floor), and R1/R2 showed
// the RA then still targets 8 waves/EU and spills the x row to scratch
// (VGPR=40, 447us = 2.15x FMA floor). Capping at 4 waves/EU gives the RA a
// 128-VGPR budget so the 64-float x row stays register-resident.
__global__ __launch_bounds__(BLK)
__attribute__((amdgpu_waves_per_eu(4, 4)))
void KMeans_assign_kernel(
    const float* __restrict__ x, const float* __restrict__ c,
    int* __restrict__ out, int n)
{
    __shared__ float sc2[KC];

    // Cooperative per-block centroid-norm precompute (0.4% overhead).
    for (int k = threadIdx.x; k < KC; k += BLK) {
        const float* crow = c + k * DIM;
        float s0 = 0.f, s1 = 0.f, s2 = 0.f, s3 = 0.f;
        #pragma unroll
        for (int d = 0; d < DIM; d += 4) {
            s0 = fmaf(crow[d + 0], crow[d + 0], s0);
            s1 = fmaf(crow[d + 1], crow[d + 1], s1);
            s2 = fmaf(crow[d + 2], crow[d + 2], s2);
            s3 = fmaf(crow[d + 3], crow[d + 3], s3);
        }
        sc2[k] = (s0 + s1) + (s2 + s3);
    }
    __syncthreads();

    const int i = blockIdx.x * BLK + threadIdx.x;
    if (i >= n) return;

    // Load this point's 64 floats into registers (float4 x16); asm pins kept
    // as insurance against remat now that the RA has budget.
    float xr[DIM];
    const float4* xv = (const float4*)(x + (size_t)i * DIM);
    #pragma unroll
    for (int j = 0; j < DIM / 4; ++j) {
        float4 v = xv[j];
        xr[4 * j + 0] = v.x;
        xr[4 * j + 1] = v.y;
        xr[4 * j + 2] = v.z;
        xr[4 * j + 3] = v.w;
    }
    #pragma unroll
    for (int d = 0; d < DIM; ++d) {
        asm volatile("" : "+v"(xr[d]));
    }

    float x20 = 0.f, x21 = 0.f, x22 = 0.f, x23 = 0.f;
    #pragma unroll
    for (int d = 0; d < DIM; d += 4) {
        x20 = fmaf(xr[d + 0], xr[d + 0], x20);
        x21 = fmaf(xr[d + 1], xr[d + 1], x21);
        x22 = fmaf(xr[d + 2], xr[d + 2], x22);
        x23 = fmaf(xr[d + 3], xr[d + 3], x23);
    }
    const float x2 = (x20 + x21) + (x22 + x23);

    float best = 3.402823466e38f;
    int   bi   = 0;
    for (int k = 0; k < KC; ++k) {
        const float* crow = c + k * DIM;  // wave-uniform -> s_load
        float d0 = 0.f, d1 = 0.f, d2a = 0.f, d3 = 0.f;
        #pragma unroll
        for (int d = 0; d < DIM; d += 4) {
            d0  = fmaf(crow[d + 0], xr[d + 0], d0);
            d1  = fmaf(crow[d + 1], xr[d + 1], d1);
            d2a = fmaf(crow[d + 2], xr[d + 2], d2a);
            d3  = fmaf(crow[d + 3], xr[d + 3], d3);
        }
        const float dot = (d0 + d1) + (d2a + d3);
        // Identical arithmetic to R1 (validated absmax 0.0).
        float d2 = (x2 + sc2[k]) - 2.0f * dot;
        d2 = fmaxf(d2, 0.0f);
        const bool lt = d2 < best;   // strict < : first-index tie-break
        best = lt ? d2 : best;
        bi   = lt ? k  : bi;
    }
    out[i] = bi;
}

extern "C" void kernel_launch(void* const* d_in, const int* in_sizes, int n_in,
                              void* d_out, int out_size, void* d_ws, size_t ws_size,
                              hipStream_t stream) {
    const float* x = (const float*)d_in[0];   // [N, 64] fp32
    const float* c = (const float*)d_in[1];   // [512, 64] fp32
    int* out = (int*)d_out;                   // [N] int32 labels
    const int n = in_sizes[0] / DIM;

    const int grid = (n + BLK - 1) / BLK;
    KMeans_assign_kernel<<<grid, BLK, 0, stream>>>(x, c, out, n);
}

// Round 4
// 501.512 us; speedup vs baseline: 1.0835x; 1.0835x over previous
//
#include <hip/hip_runtime.h>

#define DIM 64
#define KC 512
#define BLK 256          // 4 waves per block
#define PT 4             // A-tiles (16 points each) per wave -> 64 points/wave
#define CG 256           // centroids per LDS group (2 groups)
#define NT (CG / 16)     // 16 centroid tiles per group
#define MARGIN 1e-3f     // cert margin >> worst-case approx error (~1.5e-4)

typedef _Float16 half8  __attribute__((ext_vector_type(8)));
typedef float    floatx4 __attribute__((ext_vector_type(4)));

// S = X·C^T fused with argmin, fp16x2 split for fp32-grade accuracy:
//   dot = xh·ch + (xh·cl2 + xl2·ch)/2048,  xl2=(x-xh)*2048 (fp16-normal range)
// Certified points (top2 gap > MARGIN) provably match R1's fp32 argmin
// (R1 measured absmax 0.0); uncertified points re-run R1's exact arithmetic.
__global__ __launch_bounds__(BLK)
__attribute__((amdgpu_waves_per_eu(2)))
void kmeans_mfma(const float* __restrict__ x, const float* __restrict__ c,
                 int* __restrict__ out, int n)
{
    // Centroid fragments stored in MFMA B-operand stream order:
    // frag (t,chunk): 64 lanes x 8 halves contiguous -> ds_read_b128, 0 conflicts.
    __shared__ _Float16 shH[NT * 2 * 64 * 8];   // 32 KB  (hi)
    __shared__ _Float16 shL[NT * 2 * 64 * 8];   // 32 KB  (lo*2048)
    __shared__ float    sc2[KC];                // 2 KB   (exact fp32 ||c||^2, R1 op order)

    const int tid  = threadIdx.x;
    const int wave = tid >> 6;
    const int lane = tid & 63;
    const int nidx = lane & 15;   // A: row m ; B: col n ; C/D: col n
    const int quad = lane >> 4;   // k-slice selector

    const long jobBase = ((long)blockIdx.x * 4 + wave) * 64;  // first point of this wave

    // ---- A fragments: 4 ptiles x 2 k-chunks, hi + scaled-lo ----
    half8 ah[PT][2], al[PT][2];
    #pragma unroll
    for (int pt = 0; pt < PT; ++pt) {
        long row = jobBase + pt * 16 + nidx;
        if (row > (long)n - 1) row = (long)n - 1;   // tail clamp (writes masked later)
        #pragma unroll
        for (int ch = 0; ch < 2; ++ch) {
            const float* xp = x + row * DIM + ch * 32 + quad * 8;
            float4 v0 = *(const float4*)xp;
            float4 v1 = *(const float4*)(xp + 4);
            float fs[8] = {v0.x, v0.y, v0.z, v0.w, v1.x, v1.y, v1.z, v1.w};
            #pragma unroll
            for (int j = 0; j < 8; ++j) {
                _Float16 h = (_Float16)fs[j];
                ah[pt][ch][j] = h;
                al[pt][ch][j] = (_Float16)((fs[j] - (float)h) * 2048.0f);
            }
        }
    }

    // ---- per-lane running argmin state: 16 points (pt, r), this lane's n only ----
    float best[PT][4], sec[PT][4];
    int   bidx[PT][4];
    #pragma unroll
    for (int pt = 0; pt < PT; ++pt)
        #pragma unroll
        for (int r = 0; r < 4; ++r) {
            best[pt][r] = 3.402823466e38f;
            sec[pt][r]  = 3.402823466e38f;
            bidx[pt][r] = 0;
        }

    for (int g = 0; g < 2; ++g) {
        if (g) __syncthreads();   // protect previous group's LDS from overwrite

        // Stage group g: convert fp32 centroids -> (hi, lo*2048) fp16 frags.
        for (int e = tid; e < CG * DIM; e += BLK) {
            const int cr = e >> 6, d = e & 63;
            const int t = cr >> 4, ni = cr & 15;
            const int ch = d >> 5, q = (d >> 3) & 3, j = d & 7;
            const int pos = (((t * 2 + ch) * 64) + (q * 16 + ni)) * 8 + j;
            const float f = c[(long)(g * CG + cr) * DIM + d];
            const _Float16 h = (_Float16)f;
            shH[pos] = h;
            shL[pos] = (_Float16)((f - (float)h) * 2048.0f);
        }
        // Exact fp32 ||c||^2 with R1's op order (used by merge AND rescan).
        for (int k = tid; k < CG; k += BLK) {
            const float* crow = c + (long)(g * CG + k) * DIM;
            float s0 = 0.f, s1 = 0.f, s2 = 0.f, s3 = 0.f;
            #pragma unroll
            for (int d = 0; d < DIM; d += 4) {
                s0 = fmaf(crow[d + 0], crow[d + 0], s0);
                s1 = fmaf(crow[d + 1], crow[d + 1], s1);
                s2 = fmaf(crow[d + 2], crow[d + 2], s2);
                s3 = fmaf(crow[d + 3], crow[d + 3], s3);
            }
            sc2[g * CG + k] = (s0 + s1) + (s2 + s3);
        }
        __syncthreads();

        for (int t = 0; t < NT; ++t) {
            const half8 bh0 = *(const half8*)&shH[((t * 2 + 0) * 64 + lane) * 8];
            const half8 bh1 = *(const half8*)&shH[((t * 2 + 1) * 64 + lane) * 8];
            const half8 bl0 = *(const half8*)&shL[((t * 2 + 0) * 64 + lane) * 8];
            const half8 bl1 = *(const half8*)&shL[((t * 2 + 1) * 64 + lane) * 8];
            const float cc2 = sc2[g * CG + t * 16 + nidx];
            const int  kidx = g * CG + t * 16 + nidx;
            #pragma unroll
            for (int pt = 0; pt < PT; ++pt) {
                floatx4 am = {0.f, 0.f, 0.f, 0.f};
                floatx4 ac = {0.f, 0.f, 0.f, 0.f};
                am = __builtin_amdgcn_mfma_f32_16x16x32_f16(ah[pt][0], bh0, am, 0, 0, 0);
                am = __builtin_amdgcn_mfma_f32_16x16x32_f16(ah[pt][1], bh1, am, 0, 0, 0);
                ac = __builtin_amdgcn_mfma_f32_16x16x32_f16(ah[pt][0], bl0, ac, 0, 0, 0);
                ac = __builtin_amdgcn_mfma_f32_16x16x32_f16(ah[pt][1], bl1, ac, 0, 0, 0);
                ac = __builtin_amdgcn_mfma_f32_16x16x32_f16(al[pt][0], bh0, ac, 0, 0, 0);
                ac = __builtin_amdgcn_mfma_f32_16x16x32_f16(al[pt][1], bh1, ac, 0, 0, 0);
                #pragma unroll
                for (int r = 0; r < 4; ++r) {
                    const float dot = fmaf(ac[r], 4.8828125e-4f, am[r]); // + corr/2048
                    const float v   = fmaf(-2.0f, dot, cc2);  // c2 - 2*dot (x2 const/point)
                    const bool lt = v < best[pt][r];          // ascending kidx => first-idx ties
                    sec[pt][r]  = fminf(sec[pt][r], lt ? best[pt][r] : v);
                    best[pt][r] = lt ? v : best[pt][r];
                    bidx[pt][r] = lt ? kidx : bidx[pt][r];
                }
            }
        }
    }

    // ---- butterfly reduce over the 16 lanes (n) of each quad ----
    #pragma unroll
    for (int off = 1; off < 16; off <<= 1) {
        #pragma unroll
        for (int pt = 0; pt < PT; ++pt)
            #pragma unroll
            for (int r = 0; r < 4; ++r) {
                const float ob = __shfl_xor(best[pt][r], off, 64);
                const int   oi = __shfl_xor(bidx[pt][r], off, 64);
                const float os = __shfl_xor(sec[pt][r],  off, 64);
                const bool lt = (ob < best[pt][r]) ||
                                (ob == best[pt][r] && oi < bidx[pt][r]);
                const float loser = lt ? best[pt][r] : ob;
                sec[pt][r]  = fminf(fminf(sec[pt][r], os), loser);
                best[pt][r] = lt ? ob : best[pt][r];
                bidx[pt][r] = lt ? oi : bidx[pt][r];
            }
    }

    // ---- write: lane (quad q, n) owns point pt=n>>2, m=q*4+(n&3) ----
    const int pt_w = nidx >> 2;
    const int r_w  = lane & 3;
    float b = 0.f, s = 0.f; int bi = 0;
    #pragma unroll
    for (int pt = 0; pt < PT; ++pt)
        #pragma unroll
        for (int r = 0; r < 4; ++r) {
            const bool m = (pt == pt_w) && (r == r_w);
            b  = m ? best[pt][r] : b;
            s  = m ? sec[pt][r]  : s;
            bi = m ? bidx[pt][r] : bi;
        }
    const long p = jobBase + (long)pt_w * 16 + quad * 4 + r_w;

    if (p < n) {
        if (s - b > MARGIN) {
            out[p] = bi;   // certified: provably equals R1's fp32 argmin
        } else {
            // Exact rescan, bit-identical to R1 (which matched ref, absmax 0.0).
            const float* xrow = x + p * DIM;
            float x20 = 0.f, x21 = 0.f, x22 = 0.f, x23 = 0.f;
            #pragma unroll
            for (int d = 0; d < DIM; d += 4) {
                x20 = fmaf(xrow[d + 0], xrow[d + 0], x20);
                x21 = fmaf(xrow[d + 1], xrow[d + 1], x21);
                x22 = fmaf(xrow[d + 2], xrow[d + 2], x22);
                x23 = fmaf(xrow[d + 3], xrow[d + 3], x23);
            }
            const float x2 = (x20 + x21) + (x22 + x23);
            float bb = 3.402823466e38f; int bbi = 0;
            for (int k = 0; k < KC; ++k) {
                const float* crow = c + k * DIM;
                float d0 = 0.f, d1 = 0.f, d2a = 0.f, d3 = 0.f;
                #pragma unroll
                for (int d = 0; d < DIM; d += 4) {
                    d0  = fmaf(crow[d + 0], xrow[d + 0], d0);
                    d1  = fmaf(crow[d + 1], xrow[d + 1], d1);
                    d2a = fmaf(crow[d + 2], xrow[d + 2], d2a);
                    d3  = fmaf(crow[d + 3], xrow[d + 3], d3);
                }
                const float dot = (d0 + d1) + (d2a + d3);
                float d2v = (x2 + sc2[k]) - 2.0f * dot;
                d2v = fmaxf(d2v, 0.0f);
                const bool l2 = d2v < bb;
                bb  = l2 ? d2v : bb;
                bbi = l2 ? k   : bbi;
            }
            out[p] = bbi;
        }
    }
}

extern "C" void kernel_launch(void* const* d_in, const int* in_sizes, int n_in,
                              void* d_out, int out_size, void* d_ws, size_t ws_size,
                              hipStream_t stream) {
    const float* x = (const float*)d_in[0];   // [N, 64] fp32
    const float* c = (const float*)d_in[1];   // [512, 64] fp32
    int* out = (int*)d_out;                   // [N] int32 labels
    const int n = in_sizes[0] / DIM;

    const int jobs   = (n + 63) / 64;         // 64 points per wave
    const int blocks = (jobs + 3) / 4;        // 4 waves per block
    kmeans_mfma<<<blocks, BLK, 0, stream>>>(x, c, out, n);
}

// Round 5
// 440.124 us; speedup vs baseline: 1.2347x; 1.1395x over previous
//
#include <hip/hip_runtime.h>

#define DIM 64
#define KC 512
#define BLK 256          // 4 waves per block
#define PT 4             // A-tiles (16 points each) per wave -> 64 points/wave
#define CG 128           // centroids per LDS group (4 groups) -> 34 KB LDS, 4 blocks/CU
#define NT (CG / 16)     // 8 centroid tiles per group
#define MARGIN 1e-3f     // cert margin >> worst-case approx error (~1.5e-4)

typedef _Float16 half8   __attribute__((ext_vector_type(8)));
typedef float    floatx4 __attribute__((ext_vector_type(4)));

// Async 16B/lane global->LDS copy: LDS dest = uniform base + lane*16 (m104).
__device__ __forceinline__ void async_cp16(_Float16* lds_base, const _Float16* g_lane) {
    __builtin_amdgcn_global_load_lds(
        (const __attribute__((address_space(1))) unsigned int*)(g_lane),
        (__attribute__((address_space(3))) unsigned int*)(lds_base),
        16, 0, 0);
}

// Precompute (every launch; d_ws is re-poisoned): centroids -> (hi, lo*2048)
// fp16 fragments in MFMA B-operand STREAM order, + exact fp32 ||c||^2 with
// R1's op order. Blocks 0..127: frags (1 elem/thread). Blocks 128..129: sc2.
__global__ __launch_bounds__(BLK) void kmeans_prep(
    const float* __restrict__ c, _Float16* __restrict__ frH,
    _Float16* __restrict__ frL, float* __restrict__ g_sc2)
{
    const int b = blockIdx.x;
    if (b < 128) {
        const int e  = b * BLK + threadIdx.x;        // 0..32767 == cr*64+d
        const int cr = e >> 6, d = e & 63;
        const int T  = cr >> 4, ni = cr & 15;        // global tile, col-in-tile
        const int ch = d >> 5, q = (d >> 3) & 3, j = d & 7;
        const int pos = ((T * 2 + ch) * 64 + (q * 16 + ni)) * 8 + j;
        const float f = c[e];
        const _Float16 h = (_Float16)f;
        frH[pos] = h;
        frL[pos] = (_Float16)((f - (float)h) * 2048.0f);
    } else {
        const int k = (b - 128) * BLK + threadIdx.x; // 0..511
        const float* crow = c + (long)k * DIM;
        float s0 = 0.f, s1 = 0.f, s2 = 0.f, s3 = 0.f;
        #pragma unroll
        for (int d = 0; d < DIM; d += 4) {
            s0 = fmaf(crow[d + 0], crow[d + 0], s0);
            s1 = fmaf(crow[d + 1], crow[d + 1], s1);
            s2 = fmaf(crow[d + 2], crow[d + 2], s2);
            s3 = fmaf(crow[d + 3], crow[d + 3], s3);
        }
        g_sc2[k] = (s0 + s1) + (s2 + s3);
    }
}

// Main: S = X·C^T fused argmin, fp16x2 split (validated R4, absmax 0.0).
// Staging is now a verbatim async LDS copy of pre-fragmented centroids:
// no conversion VALU, no VGPR round-trip. 34 KB LDS -> 4 blocks/CU.
__global__ __launch_bounds__(BLK)
__attribute__((amdgpu_waves_per_eu(2)))   // R4: yields VGPR=100 <= 128, fits 4 waves/EU
void kmeans_mfma(const float* __restrict__ x, const float* __restrict__ c,
                 const _Float16* __restrict__ frH, const _Float16* __restrict__ frL,
                 const float* __restrict__ g_sc2, int* __restrict__ out, int n)
{
    __shared__ _Float16 shH[NT * 2 * 64 * 8];   // 16 KB (hi frags, stream order)
    __shared__ _Float16 shL[NT * 2 * 64 * 8];   // 16 KB (lo*2048 frags)
    __shared__ float    s_sc2[KC];              // 2 KB  (full exact ||c||^2)

    const int tid  = threadIdx.x;
    const int wave = tid >> 6;
    const int lane = tid & 63;
    const int nidx = lane & 15;
    const int quad = lane >> 4;

    const long jobBase = ((long)blockIdx.x * 4 + wave) * 64;

    // ---- A fragments: 4 ptiles x 2 k-chunks, hi + scaled-lo (R4-identical) ----
    half8 ah[PT][2], al[PT][2];
    #pragma unroll
    for (int pt = 0; pt < PT; ++pt) {
        long row = jobBase + pt * 16 + nidx;
        if (row > (long)n - 1) row = (long)n - 1;
        #pragma unroll
        for (int ch = 0; ch < 2; ++ch) {
            const float* xp = x + row * DIM + ch * 32 + quad * 8;
            float4 v0 = *(const float4*)xp;
            float4 v1 = *(const float4*)(xp + 4);
            float fs[8] = {v0.x, v0.y, v0.z, v0.w, v1.x, v1.y, v1.z, v1.w};
            #pragma unroll
            for (int j = 0; j < 8; ++j) {
                _Float16 h = (_Float16)fs[j];
                ah[pt][ch][j] = h;
                al[pt][ch][j] = (_Float16)((fs[j] - (float)h) * 2048.0f);
            }
        }
    }

    float best[PT][4], sec[PT][4];
    int   bidx[PT][4];
    #pragma unroll
    for (int pt = 0; pt < PT; ++pt)
        #pragma unroll
        for (int r = 0; r < 4; ++r) {
            best[pt][r] = 3.402823466e38f;
            sec[pt][r]  = 3.402823466e38f;
            bidx[pt][r] = 0;
        }

    for (int g = 0; g < 4; ++g) {
        if (g) __syncthreads();   // previous group's compute done before overwrite

        // Stage group g: verbatim async copy, 16 KB hi + 16 KB lo.
        // 1024 16B-chunks each; wave takes 256 (4 instrs), dest uniform/instr.
        {
            const _Float16* srcH = frH + (long)g * (NT * 2 * 64 * 8);
            const _Float16* srcL = frL + (long)g * (NT * 2 * 64 * 8);
            #pragma unroll
            for (int ii = 0; ii < 4; ++ii) {
                const int chunk = wave * 256 + ii * 64;   // wave-uniform
                async_cp16(shH + (long)chunk * 8, srcH + (long)(chunk + lane) * 8);
                async_cp16(shL + (long)chunk * 8, srcL + (long)(chunk + lane) * 8);
            }
        }
        if (g == 0) {  // stage full sc2 once
            for (int k2 = tid; k2 < KC; k2 += BLK) s_sc2[k2] = g_sc2[k2];
        }
        __syncthreads();  // drains vmcnt (async LDS writes) + lgkm

        #pragma unroll 2
        for (int t = 0; t < NT; ++t) {
            const half8 bh0 = *(const half8*)&shH[((t * 2 + 0) * 64 + lane) * 8];
            const half8 bh1 = *(const half8*)&shH[((t * 2 + 1) * 64 + lane) * 8];
            const half8 bl0 = *(const half8*)&shL[((t * 2 + 0) * 64 + lane) * 8];
            const half8 bl1 = *(const half8*)&shL[((t * 2 + 1) * 64 + lane) * 8];
            const float cc2 = s_sc2[g * CG + t * 16 + nidx];
            const int  kidx = g * CG + t * 16 + nidx;
            #pragma unroll
            for (int pt = 0; pt < PT; ++pt) {
                floatx4 am = {0.f, 0.f, 0.f, 0.f};
                floatx4 ac = {0.f, 0.f, 0.f, 0.f};
                am = __builtin_amdgcn_mfma_f32_16x16x32_f16(ah[pt][0], bh0, am, 0, 0, 0);
                am = __builtin_amdgcn_mfma_f32_16x16x32_f16(ah[pt][1], bh1, am, 0, 0, 0);
                ac = __builtin_amdgcn_mfma_f32_16x16x32_f16(ah[pt][0], bl0, ac, 0, 0, 0);
                ac = __builtin_amdgcn_mfma_f32_16x16x32_f16(ah[pt][1], bl1, ac, 0, 0, 0);
                ac = __builtin_amdgcn_mfma_f32_16x16x32_f16(al[pt][0], bh0, ac, 0, 0, 0);
                ac = __builtin_amdgcn_mfma_f32_16x16x32_f16(al[pt][1], bh1, ac, 0, 0, 0);
                #pragma unroll
                for (int r = 0; r < 4; ++r) {
                    const float dot = fmaf(ac[r], 4.8828125e-4f, am[r]);
                    const float v   = fmaf(-2.0f, dot, cc2);
                    const bool lt = v < best[pt][r];
                    sec[pt][r]  = fminf(sec[pt][r], lt ? best[pt][r] : v);
                    best[pt][r] = lt ? v : best[pt][r];
                    bidx[pt][r] = lt ? kidx : bidx[pt][r];
                }
            }
        }
    }

    // ---- butterfly reduce over the 16 lanes (n) of each quad (R4-identical) ----
    #pragma unroll
    for (int off = 1; off < 16; off <<= 1) {
        #pragma unroll
        for (int pt = 0; pt < PT; ++pt)
            #pragma unroll
            for (int r = 0; r < 4; ++r) {
                const float ob = __shfl_xor(best[pt][r], off, 64);
                const int   oi = __shfl_xor(bidx[pt][r], off, 64);
                const float os = __shfl_xor(sec[pt][r],  off, 64);
                const bool lt = (ob < best[pt][r]) ||
                                (ob == best[pt][r] && oi < bidx[pt][r]);
                const float loser = lt ? best[pt][r] : ob;
                sec[pt][r]  = fminf(fminf(sec[pt][r], os), loser);
                best[pt][r] = lt ? ob : best[pt][r];
                bidx[pt][r] = lt ? oi : bidx[pt][r];
            }
    }

    const int pt_w = nidx >> 2;
    const int r_w  = lane & 3;
    float b = 0.f, s = 0.f; int bi = 0;
    #pragma unroll
    for (int pt = 0; pt < PT; ++pt)
        #pragma unroll
        for (int r = 0; r < 4; ++r) {
            const bool m = (pt == pt_w) && (r == r_w);
            b  = m ? best[pt][r] : b;
            s  = m ? sec[pt][r]  : s;
            bi = m ? bidx[pt][r] : bi;
        }
    const long p = jobBase + (long)pt_w * 16 + quad * 4 + r_w;

    if (p < n) {
        if (s - b > MARGIN) {
            out[p] = bi;   // certified == R1 fp32 argmin (R1 absmax 0.0)
        } else {
            // Exact rescan, bit-identical to R1.
            const float* xrow = x + p * DIM;
            float x20 = 0.f, x21 = 0.f, x22 = 0.f, x23 = 0.f;
            #pragma unroll
            for (int d = 0; d < DIM; d += 4) {
                x20 = fmaf(xrow[d + 0], xrow[d + 0], x20);
                x21 = fmaf(xrow[d + 1], xrow[d + 1], x21);
                x22 = fmaf(xrow[d + 2], xrow[d + 2], x22);
                x23 = fmaf(xrow[d + 3], xrow[d + 3], x23);
            }
            const float x2 = (x20 + x21) + (x22 + x23);
            float bb = 3.402823466e38f; int bbi = 0;
            for (int k = 0; k < KC; ++k) {
                const float* crow = c + k * DIM;
                float d0 = 0.f, d1 = 0.f, d2a = 0.f, d3 = 0.f;
                #pragma unroll
                for (int d = 0; d < DIM; d += 4) {
                    d0  = fmaf(crow[d + 0], xrow[d + 0], d0);
                    d1  = fmaf(crow[d + 1], xrow[d + 1], d1);
                    d2a = fmaf(crow[d + 2], xrow[d + 2], d2a);
                    d3  = fmaf(crow[d + 3], xrow[d + 3], d3);
                }
                const float dot = (d0 + d1) + (d2a + d3);
                float d2v = (x2 + s_sc2[k]) - 2.0f * dot;
                d2v = fmaxf(d2v, 0.0f);
                const bool l2 = d2v < bb;
                bb  = l2 ? d2v : bb;
                bbi = l2 ? k   : bbi;
            }
            out[p] = bbi;
        }
    }
}

extern "C" void kernel_launch(void* const* d_in, const int* in_sizes, int n_in,
                              void* d_out, int out_size, void* d_ws, size_t ws_size,
                              hipStream_t stream) {
    const float* x = (const float*)d_in[0];   // [N, 64] fp32
    const float* c = (const float*)d_in[1];   // [512, 64] fp32
    int* out = (int*)d_out;                   // [N] int32 labels
    const int n = in_sizes[0] / DIM;

    _Float16* frH  = (_Float16*)d_ws;                 // 64 KB
    _Float16* frL  = frH + (KC * DIM);                // 64 KB
    float*    gsc2 = (float*)(frL + (KC * DIM));      // 2 KB   (total 130 KB of ws)

    kmeans_prep<<<130, BLK, 0, stream>>>(c, frH, frL, gsc2);

    const int jobs   = (n + 63) / 64;         // 64 points per wave
    const int blocks = (jobs + 3) / 4;        // 4 waves per block
    kmeans_mfma<<<blocks, BLK, 0, stream>>>(x, c, frH, frL, gsc2, out, n);
}

// Round 6
// 335.293 us; speedup vs baseline: 1.6207x; 1.3127x over previous
//
#include <hip/hip_runtime.h>

#define DIM 64
#define KC 512
#define BLK 256          // 4 waves per block
#define PT 4             // A-tiles (16 points each) per wave -> 64 points/wave
#define CG 128           // centroids per LDS group (4 groups) -> 34 KB LDS
#define NT (CG / 16)     // 8 centroid tiles per group
#define MARGIN 1e-3f     // cert margin > worst-case split error (~5e-4)
#define LIST_CAP 500000

typedef _Float16 half8   __attribute__((ext_vector_type(8)));
typedef float    floatx4 __attribute__((ext_vector_type(4)));

__device__ __forceinline__ void async_cp16(_Float16* lds_base, const _Float16* g_lane) {
    __builtin_amdgcn_global_load_lds(
        (const __attribute__((address_space(1))) unsigned int*)(g_lane),
        (__attribute__((address_space(3))) unsigned int*)(lds_base),
        16, 0, 0);
}

// Prep (every launch; d_ws re-poisoned): centroid (hi, lo*2048) fp16 frags in
// MFMA B-stream order + exact fp32 ||c||^2 in R1 op order + zero rescan count.
__global__ __launch_bounds__(BLK) void kmeans_prep(
    const float* __restrict__ c, _Float16* __restrict__ frH,
    _Float16* __restrict__ frL, float* __restrict__ g_sc2,
    unsigned* __restrict__ rs_count)
{
    const int b = blockIdx.x;
    if (b < 128) {
        const int e  = b * BLK + threadIdx.x;
        const int cr = e >> 6, d = e & 63;
        const int T  = cr >> 4, ni = cr & 15;
        const int ch = d >> 5, q = (d >> 3) & 3, j = d & 7;
        const int pos = ((T * 2 + ch) * 64 + (q * 16 + ni)) * 8 + j;
        const float f = c[e];
        const _Float16 h = (_Float16)f;
        frH[pos] = h;
        frL[pos] = (_Float16)((f - (float)h) * 2048.0f);
    } else {
        if (b == 128 && threadIdx.x == 0) *rs_count = 0u;
        const int k = (b - 128) * BLK + threadIdx.x;
        const float* crow = c + (long)k * DIM;
        float s0 = 0.f, s1 = 0.f, s2 = 0.f, s3 = 0.f;
        #pragma unroll
        for (int d = 0; d < DIM; d += 4) {
            s0 = fmaf(crow[d + 0], crow[d + 0], s0);
            s1 = fmaf(crow[d + 1], crow[d + 1], s1);
            s2 = fmaf(crow[d + 2], crow[d + 2], s2);
            s3 = fmaf(crow[d + 3], crow[d + 3], s3);
        }
        g_sc2[k] = (s0 + s1) + (s2 + s3);
    }
}

// Main: MFMA fp16x2-split distance + fused argmin (R5-identical compute path,
// validated absmax 0.0). Uncertified points are APPENDED to a list instead of
// rescanned in-kernel — R5's 80%-of-waves divergent 22k-cycle tails were the
// occupancy/MfmaUtil killer (Occ 9%, MfmaUtil 12%).
__global__ __launch_bounds__(BLK)
__attribute__((amdgpu_waves_per_eu(2)))   // keeps A-frags/state unspilled (VGPR~116)
void kmeans_mfma(const float* __restrict__ x,
                 const _Float16* __restrict__ frH, const _Float16* __restrict__ frL,
                 const float* __restrict__ g_sc2, int* __restrict__ out,
                 unsigned* __restrict__ rs_count, int* __restrict__ rs_list, int n)
{
    __shared__ _Float16 shH[NT * 2 * 64 * 8];   // 16 KB
    __shared__ _Float16 shL[NT * 2 * 64 * 8];   // 16 KB
    __shared__ float    s_sc2[KC];              // 2 KB

    const int tid  = threadIdx.x;
    const int wave = tid >> 6;
    const int lane = tid & 63;
    const int nidx = lane & 15;
    const int quad = lane >> 4;

    const long jobBase = ((long)blockIdx.x * 4 + wave) * 64;

    half8 ah[PT][2], al[PT][2];
    #pragma unroll
    for (int pt = 0; pt < PT; ++pt) {
        long row = jobBase + pt * 16 + nidx;
        if (row > (long)n - 1) row = (long)n - 1;
        #pragma unroll
        for (int ch = 0; ch < 2; ++ch) {
            const float* xp = x + row * DIM + ch * 32 + quad * 8;
            float4 v0 = *(const float4*)xp;
            float4 v1 = *(const float4*)(xp + 4);
            float fs[8] = {v0.x, v0.y, v0.z, v0.w, v1.x, v1.y, v1.z, v1.w};
            #pragma unroll
            for (int j = 0; j < 8; ++j) {
                _Float16 h = (_Float16)fs[j];
                ah[pt][ch][j] = h;
                al[pt][ch][j] = (_Float16)((fs[j] - (float)h) * 2048.0f);
            }
        }
    }

    float best[PT][4], sec[PT][4];
    int   bidx[PT][4];
    #pragma unroll
    for (int pt = 0; pt < PT; ++pt)
        #pragma unroll
        for (int r = 0; r < 4; ++r) {
            best[pt][r] = 3.402823466e38f;
            sec[pt][r]  = 3.402823466e38f;
            bidx[pt][r] = 0;
        }

    for (int g = 0; g < 4; ++g) {
        if (g) __syncthreads();

        {
            const _Float16* srcH = frH + (long)g * (NT * 2 * 64 * 8);
            const _Float16* srcL = frL + (long)g * (NT * 2 * 64 * 8);
            #pragma unroll
            for (int ii = 0; ii < 4; ++ii) {
                const int chunk = wave * 256 + ii * 64;   // wave-uniform
                async_cp16(shH + (long)chunk * 8, srcH + (long)(chunk + lane) * 8);
                async_cp16(shL + (long)chunk * 8, srcL + (long)(chunk + lane) * 8);
            }
        }
        if (g == 0) {
            for (int k2 = tid; k2 < KC; k2 += BLK) s_sc2[k2] = g_sc2[k2];
        }
        __syncthreads();

        #pragma unroll 2
        for (int t = 0; t < NT; ++t) {
            const half8 bh0 = *(const half8*)&shH[((t * 2 + 0) * 64 + lane) * 8];
            const half8 bh1 = *(const half8*)&shH[((t * 2 + 1) * 64 + lane) * 8];
            const half8 bl0 = *(const half8*)&shL[((t * 2 + 0) * 64 + lane) * 8];
            const half8 bl1 = *(const half8*)&shL[((t * 2 + 1) * 64 + lane) * 8];
            const float cc2 = s_sc2[g * CG + t * 16 + nidx];
            const int  kidx = g * CG + t * 16 + nidx;
            #pragma unroll
            for (int pt = 0; pt < PT; ++pt) {
                floatx4 am = {0.f, 0.f, 0.f, 0.f};
                floatx4 ac = {0.f, 0.f, 0.f, 0.f};
                am = __builtin_amdgcn_mfma_f32_16x16x32_f16(ah[pt][0], bh0, am, 0, 0, 0);
                am = __builtin_amdgcn_mfma_f32_16x16x32_f16(ah[pt][1], bh1, am, 0, 0, 0);
                ac = __builtin_amdgcn_mfma_f32_16x16x32_f16(ah[pt][0], bl0, ac, 0, 0, 0);
                ac = __builtin_amdgcn_mfma_f32_16x16x32_f16(ah[pt][1], bl1, ac, 0, 0, 0);
                ac = __builtin_amdgcn_mfma_f32_16x16x32_f16(al[pt][0], bh0, ac, 0, 0, 0);
                ac = __builtin_amdgcn_mfma_f32_16x16x32_f16(al[pt][1], bh1, ac, 0, 0, 0);
                #pragma unroll
                for (int r = 0; r < 4; ++r) {
                    const float dot = fmaf(ac[r], 4.8828125e-4f, am[r]);
                    const float v   = fmaf(-2.0f, dot, cc2);
                    const bool lt = v < best[pt][r];
                    sec[pt][r]  = fminf(sec[pt][r], lt ? best[pt][r] : v);
                    best[pt][r] = lt ? v : best[pt][r];
                    bidx[pt][r] = lt ? kidx : bidx[pt][r];
                }
            }
        }
    }

    #pragma unroll
    for (int off = 1; off < 16; off <<= 1) {
        #pragma unroll
        for (int pt = 0; pt < PT; ++pt)
            #pragma unroll
            for (int r = 0; r < 4; ++r) {
                const float ob = __shfl_xor(best[pt][r], off, 64);
                const int   oi = __shfl_xor(bidx[pt][r], off, 64);
                const float os = __shfl_xor(sec[pt][r],  off, 64);
                const bool lt = (ob < best[pt][r]) ||
                                (ob == best[pt][r] && oi < bidx[pt][r]);
                const float loser = lt ? best[pt][r] : ob;
                sec[pt][r]  = fminf(fminf(sec[pt][r], os), loser);
                best[pt][r] = lt ? ob : best[pt][r];
                bidx[pt][r] = lt ? oi : bidx[pt][r];
            }
    }

    const int pt_w = nidx >> 2;
    const int r_w  = lane & 3;
    float b = 0.f, s = 0.f; int bi = 0;
    #pragma unroll
    for (int pt = 0; pt < PT; ++pt)
        #pragma unroll
        for (int r = 0; r < 4; ++r) {
            const bool m = (pt == pt_w) && (r == r_w);
            b  = m ? best[pt][r] : b;
            s  = m ? sec[pt][r]  : s;
            bi = m ? bidx[pt][r] : bi;
        }
    const long p = jobBase + (long)pt_w * 16 + quad * 4 + r_w;

    if (p < n) {
        out[p] = bi;                       // provisional (exact if certified)
        if (!(s - b > MARGIN)) {           // uncertified -> defer exact rescan
            const unsigned idx = atomicAdd(rs_count, 1u);
            if (idx < LIST_CAP) rs_list[idx] = (int)p;
        }
    }
}

// Exact rescan: one wave per listed point; lane handles k = lane*8..lane*8+7
// with R1's exact fma chains; lexicographic (val, idx) butterfly == R1's
// sequential strict-< first-index tie-break.
__global__ __launch_bounds__(BLK) void kmeans_rescan(
    const float* __restrict__ x, const float* __restrict__ c,
    const float* __restrict__ g_sc2, const unsigned* __restrict__ rs_count,
    const int* __restrict__ rs_list, int* __restrict__ out)
{
    const int lane  = threadIdx.x & 63;
    const int gwave = (blockIdx.x * BLK + threadIdx.x) >> 6;
    const int nwave = gridDim.x * (BLK / 64);
    unsigned cnt = *rs_count;
    if (cnt > LIST_CAP) cnt = LIST_CAP;

    for (unsigned j = gwave; j < cnt; j += nwave) {
        const int p = rs_list[j];
        const float* xrow = x + (long)p * DIM;

        float x20 = 0.f, x21 = 0.f, x22 = 0.f, x23 = 0.f;
        #pragma unroll
        for (int d = 0; d < DIM; d += 4) {
            x20 = fmaf(xrow[d + 0], xrow[d + 0], x20);
            x21 = fmaf(xrow[d + 1], xrow[d + 1], x21);
            x22 = fmaf(xrow[d + 2], xrow[d + 2], x22);
            x23 = fmaf(xrow[d + 3], xrow[d + 3], x23);
        }
        const float x2 = (x20 + x21) + (x22 + x23);

        float bb = 3.402823466e38f; int bbi = 0x7fffffff;
        #pragma unroll
        for (int kk = 0; kk < 8; ++kk) {
            const int k = lane * 8 + kk;     // ascending within lane
            const float* crow = c + (long)k * DIM;
            float d0 = 0.f, d1 = 0.f, d2a = 0.f, d3 = 0.f;
            #pragma unroll
            for (int d = 0; d < DIM; d += 4) {
                d0  = fmaf(crow[d + 0], xrow[d + 0], d0);
                d1  = fmaf(crow[d + 1], xrow[d + 1], d1);
                d2a = fmaf(crow[d + 2], xrow[d + 2], d2a);
                d3  = fmaf(crow[d + 3], xrow[d + 3], d3);
            }
            const float dot = (d0 + d1) + (d2a + d3);
            float d2v = (x2 + g_sc2[k]) - 2.0f * dot;
            d2v = fmaxf(d2v, 0.0f);
            const bool l2 = d2v < bb;        // strict < keeps lowest k
            bb  = l2 ? d2v : bb;
            bbi = l2 ? k   : bbi;
        }
        #pragma unroll
        for (int off = 1; off < 64; off <<= 1) {
            const float ob = __shfl_xor(bb, off, 64);
            const int   oi = __shfl_xor(bbi, off, 64);
            const bool take = (ob < bb) || (ob == bb && oi < bbi);
            bb  = take ? ob : bb;
            bbi = take ? oi : bbi;
        }
        if (lane == 0) out[p] = bbi;
    }
}

extern "C" void kernel_launch(void* const* d_in, const int* in_sizes, int n_in,
                              void* d_out, int out_size, void* d_ws, size_t ws_size,
                              hipStream_t stream) {
    const float* x = (const float*)d_in[0];   // [N, 64] fp32
    const float* c = (const float*)d_in[1];   // [512, 64] fp32
    int* out = (int*)d_out;                   // [N] int32 labels
    const int n = in_sizes[0] / DIM;

    _Float16* frH   = (_Float16*)d_ws;                 // 64 KB
    _Float16* frL   = frH + (KC * DIM);                // 64 KB
    float*    gsc2  = (float*)(frL + (KC * DIM));      // 2 KB
    unsigned* cnt   = (unsigned*)(gsc2 + KC);          // 16 B slot
    int*      rlist = (int*)(cnt + 4);                 // <= 2 MB

    kmeans_prep<<<130, BLK, 0, stream>>>(c, frH, frL, gsc2, cnt);

    const int jobs   = (n + 63) / 64;
    const int blocks = (jobs + 3) / 4;
    kmeans_mfma<<<blocks, BLK, 0, stream>>>(x, frH, frL, gsc2, out, cnt, rlist, n);

    kmeans_rescan<<<512, BLK, 0, stream>>>(x, c, gsc2, cnt, rlist, out);
}